// Round 7
// baseline (557.197 us; speedup 1.0000x reference)
//
#include <hip/hip_runtime.h>
#include <hip/hip_bf16.h>
#include <cstdint>
#include <cstddef>

#define IN_CH 312
#define HID 256

typedef __attribute__((ext_vector_type(8))) short bf16x8;
typedef __attribute__((ext_vector_type(4))) float f32x4;
typedef __attribute__((ext_vector_type(8))) unsigned short ushort8;

__device__ __forceinline__ unsigned short f2bf(float f) {
    union { float f; unsigned u; } v; v.f = f;
    const unsigned r = v.u + 0x7FFFu + ((v.u >> 16) & 1u);  // RNE
    return (unsigned short)(r >> 16);
}
__device__ __forceinline__ float bf2f(unsigned short s) {
    union { unsigned u; float f; } v; v.u = (unsigned)s << 16;
    return v.f;
}
__device__ __forceinline__ void gload_lds16(const void* g, void* l) {
    __builtin_amdgcn_global_load_lds(
        (const __attribute__((address_space(1))) void*)g,
        (__attribute__((address_space(3))) void*)l, 16, 0, 0);
}

// ---------------------------------------------------------------------------
// Index dtype detector (int64 vs int32 edge_index).
// ---------------------------------------------------------------------------
__global__ void detect_idx_kernel(const void* __restrict__ ei, int* __restrict__ flag) {
    if (blockIdx.x == 0 && threadIdx.x == 0) {
        const int* p = (const int*)ei;
        int ok = 1;
        for (int i = 0; i < 64; ++i) ok &= (p[2 * i + 1] == 0);
        *flag = ok;
    }
}
__device__ __forceinline__ long long load_idx(const void* ei, long long i, bool is64) {
    return is64 ? ((const long long*)ei)[i] : (long long)((const int*)ei)[i];
}

// ---------------------------------------------------------------------------
// CSR build (unordered groups): histogram -> atomic group-offset assignment
// -> atomic-cursor fill. Group placement nondeterministic, membership exact.
// ---------------------------------------------------------------------------
__global__ void hist_kernel(const void* __restrict__ ei, const int* __restrict__ flag,
                            int* __restrict__ cnt, int E) {
    const int i = blockIdx.x * blockDim.x + threadIdx.x;
    if (i >= E) return;
    const bool is64 = (*flag != 0);
    atomicAdd(&cnt[load_idx(ei, (long long)E + i, is64)], 1);
}

__global__ void offsets_kernel(const int* __restrict__ cnt, int* __restrict__ counter,
                               int* __restrict__ beg, int* __restrict__ cur, int n) {
    const int i = blockIdx.x * blockDim.x + threadIdx.x;
    if (i >= n) return;
    const int b = atomicAdd(counter, cnt[i]);
    beg[i] = b;
    cur[i] = b;
}

__global__ void fill_kernel(const void* __restrict__ ei, const int* __restrict__ flag,
                            int* __restrict__ cur, int* __restrict__ col, int E) {
    const int i = blockIdx.x * blockDim.x + threadIdx.x;
    if (i >= E) return;
    const bool is64 = (*flag != 0);
    const long long s = load_idx(ei, i, is64);
    const long long d = load_idx(ei, (long long)E + i, is64);
    col[atomicAdd(&cur[d], 1)] = (int)s;
}

// WcatT[c][k] = (c<256 ? Wl[k][c] : Wr[k][c-256]), bf16, k >= K zero-padded.
__global__ void convert_w_kernel(const float* __restrict__ Wl, const float* __restrict__ Wr,
                                 unsigned short* __restrict__ wt, int K, int Kpad) {
    const int tid = blockIdx.x * blockDim.x + threadIdx.x;
    if (tid >= 512 * Kpad) return;
    const int c = tid / Kpad;
    const int k = tid % Kpad;
    float v = 0.f;
    if (k < K) v = (c < 256) ? Wl[(size_t)k * 256 + c] : Wr[(size_t)k * 256 + (c - 256)];
    wt[(size_t)c * Kpad + k] = f2bf(v);
}

// ---------------------------------------------------------------------------
// MFMA GEMM, col-blocks-inside: each block owns a 128-row slab and loops over
// the 4 col-blocks (cb) of the 512-wide output, full K-loop each. A rows are
// HBM-fetched once (cb>0 re-stages hit this block's own fresh L2 lines —
// within-block temporal locality is XCD-safe, unlike cross-block).
// 128x128 tile, BK=64, 4 waves (2x2), 16x16x32 bf16 MFMA, 32 KB LDS.
//   AFP32: A fp32 [M][312] reg-staged (float4 -> cvt -> swizzled ds_write).
//   else   A bf16 [M][KPAD] via global_load_lds (pre-swizzled source).
// Output: cb<2 -> Y bf16; cb>=2 -> Z = acc+bias (ZBF16 ? bf16 : fp32).
// bf16 outputs via LDS-staged transpose -> ushort8 coalesced stores.
// ---------------------------------------------------------------------------
template <int KPAD, bool AFP32, bool ZBF16>
__global__ __launch_bounds__(256) void mfma_gemm_kernel(
    const void* __restrict__ Avoid,         // [M][312] f32  or  [M][KPAD] bf16
    const unsigned short* __restrict__ WT,  // [512][KPAD] bf16
    const float* __restrict__ bias,         // [256]
    unsigned short* __restrict__ Y,         // [M][256] bf16
    void* __restrict__ Z,                   // [M][256] bf16 or fp32
    int M)
{
    __shared__ __align__(16) char smem[32768];
    short* a_lds = (short*)smem;             // [128*64] bf16 (16 KB)
    short* b_lds = (short*)(smem + 16384);   // [128*64] bf16 (16 KB)

    const int lane = threadIdx.x & 63;
    const int wid  = threadIdx.x >> 6;
    const int wr = wid >> 1, wc = wid & 1;
    const int r0 = blockIdx.x * 128;

    // gload staging geometry: wave-load ld covers tile rows ld*8..ld*8+7;
    // lane l -> row ld*8 + (l>>3), source 16B chunk (l&7) ^ (l>>3).
    const int ldrow  = lane >> 3;
    const int schunk = (lane & 7) ^ ldrow;

    for (int cb = 0; cb < 4; ++cb) {
        const int c0 = cb * 128;

        f32x4 acc[4][4];
        #pragma unroll
        for (int i = 0; i < 4; ++i)
            #pragma unroll
            for (int j = 0; j < 4; ++j) acc[i][j] = (f32x4)0.f;

        for (int kb = 0; kb < KPAD; kb += 64) {
            __syncthreads();  // prior compute / epilogue reads done
            // ---- B tile: 128 rows x 128B, 16 wave-loads ----
            #pragma unroll
            for (int j = 0; j < 4; ++j) {
                const int ld = wid * 4 + j;
                const int trow = ld * 8 + ldrow;
                gload_lds16(WT + (size_t)(c0 + trow) * KPAD + kb + schunk * 8,
                            (char*)b_lds + ld * 1024);
            }
            // ---- A tile: 128 rows x 128B ----
            if (AFP32) {
                const float* A = (const float*)Avoid;  // stride IN_CH
                #pragma unroll
                for (int g = 0; g < 2; ++g) {
                    float4 v[4];
                    #pragma unroll
                    for (int it = 0; it < 4; ++it) {
                        const int idx = (int)threadIdx.x + (g * 4 + it) * 256;
                        const int row = idx >> 4, q = idx & 15;
                        const int gr = min(r0 + row, M - 1);
                        const int gk = kb + q * 4;  // quad-aligned; IN_CH%4==0
                        v[it] = (gk < IN_CH)
                            ? *(const float4*)(A + (size_t)gr * IN_CH + gk)
                            : make_float4(0.f, 0.f, 0.f, 0.f);
                    }
                    #pragma unroll
                    for (int it = 0; it < 4; ++it) {
                        const int idx = (int)threadIdx.x + (g * 4 + it) * 256;
                        const int row = idx >> 4, q = idx & 15;
                        ushort4 b4;
                        b4.x = f2bf(v[it].x); b4.y = f2bf(v[it].y);
                        b4.z = f2bf(v[it].z); b4.w = f2bf(v[it].w);
                        const int byte = row * 128 + (((q >> 1) ^ (row & 7)) * 16) + (q & 1) * 8;
                        *(ushort4*)((char*)a_lds + byte) = b4;
                    }
                }
            } else {
                const unsigned short* A = (const unsigned short*)Avoid;  // stride KPAD
                #pragma unroll
                for (int j = 0; j < 4; ++j) {
                    const int ld = wid * 4 + j;
                    const int trow = ld * 8 + ldrow;
                    const int gr = min(r0 + trow, M - 1);
                    gload_lds16(A + (size_t)gr * KPAD + kb + schunk * 8,
                                (char*)a_lds + ld * 1024);
                }
            }
            __syncthreads();

            #pragma unroll
            for (int ks = 0; ks < 2; ++ks) {
                bf16x8 af[4], bg[4];
                #pragma unroll
                for (int f = 0; f < 4; ++f) {
                    const int arow = wr * 64 + f * 16 + (lane & 15);
                    const int ach  = (ks * 4 + (lane >> 4)) ^ (arow & 7);
                    af[f] = *(const bf16x8*)((const char*)a_lds + arow * 128 + ach * 16);
                    const int brow = wc * 64 + f * 16 + (lane & 15);
                    const int bch  = (ks * 4 + (lane >> 4)) ^ (brow & 7);
                    bg[f] = *(const bf16x8*)((const char*)b_lds + brow * 128 + bch * 16);
                }
                #pragma unroll
                for (int fm = 0; fm < 4; ++fm)
                    #pragma unroll
                    for (int fn = 0; fn < 4; ++fn)
                        acc[fm][fn] = __builtin_amdgcn_mfma_f32_16x16x32_bf16(
                            af[fm], bg[fn], acc[fm][fn], 0, 0, 0);
            }
        }

        // epilogue for this cb. C/D layout: col=lane&15, row=(lane>>4)*4+reg
        const bool isY = (cb < 2);
        const int cloc = wc * 64 + (lane & 15);

        if (isY || ZBF16) {
            // bf16 output via LDS transpose, two 64-row halves (reuses smem)
            constexpr int CST = 136;  // shorts; keeps 16B align, spreads banks
            short* c_lds = (short*)smem;
            float bv4[4];
            #pragma unroll
            for (int fn = 0; fn < 4; ++fn) {
                const int bidx = max(0, c0 - 256) + cloc + fn * 16;
                bv4[fn] = isY ? 0.f : bias[bidx];
            }
            #pragma unroll
            for (int h = 0; h < 2; ++h) {
                __syncthreads();
                if (wr == h) {
                    #pragma unroll
                    for (int fm = 0; fm < 4; ++fm)
                        #pragma unroll
                        for (int fn = 0; fn < 4; ++fn)
                            #pragma unroll
                            for (int r = 0; r < 4; ++r)
                                c_lds[(fm * 16 + (lane >> 4) * 4 + r) * CST + cloc + fn * 16] =
                                    (short)f2bf(acc[fm][fn][r] + bv4[fn]);
                }
                __syncthreads();
                const int row = (int)threadIdx.x >> 2;          // 0..63
                const int cbyte = ((int)threadIdx.x & 3) * 32;  // 0,32,64,96
                const int gr = r0 + h * 64 + row;
                if (gr < M) {
                    unsigned short* dst = isY
                        ? (Y + (size_t)gr * 256 + c0 + cbyte)
                        : ((unsigned short*)Z + (size_t)gr * 256 + (c0 - 256) + cbyte);
                    #pragma unroll
                    for (int j = 0; j < 4; ++j)
                        *(ushort8*)(dst + j * 8) =
                            *(const ushort8*)&c_lds[row * CST + cbyte + j * 8];
                }
            }
        } else {
            // Z fp32 direct scalar stores (layer 2; in-place target in d_out)
            const int rbase = r0 + wr * 64 + (lane >> 4) * 4;
            #pragma unroll
            for (int fn = 0; fn < 4; ++fn) {
                const int gc = (c0 - 256) + cloc + fn * 16;
                const float bvv = bias[gc];
                #pragma unroll
                for (int fm = 0; fm < 4; ++fm)
                    #pragma unroll
                    for (int r = 0; r < 4; ++r) {
                        const int gr = rbase + fm * 16 + r;
                        if (gr < M)
                            ((float*)Z)[(size_t)gr * 256 + gc] = acc[fm][fn][r] + bvv;
                    }
            }
        }
    }
}

// ---------------------------------------------------------------------------
// Gather aggregation over bf16 y: out[i] = act( mean_{e}(y[col[e]]) + Z[i] ).
// LAYER1: Z bf16, act=relu, write bf16 h. else: Z fp32, write fp32 d_out.
// Unroll-4 with two accumulator chains for ILP.
// ---------------------------------------------------------------------------
template <bool LAYER1>
__global__ void gather_agg_kernel(const unsigned short* __restrict__ Y,
                                  const int* __restrict__ beg_arr,
                                  const int* __restrict__ cnt,
                                  const int* __restrict__ col,
                                  const void* __restrict__ Z,
                                  void* __restrict__ OUT, int N)
{
    const long long gw = ((long long)blockIdx.x * blockDim.x + threadIdx.x) >> 6;
    if (gw >= N) return;
    const int w = (int)gw;
    const int lane = threadIdx.x & 63;
    const int c4 = lane * 4;
    const int beg = beg_arr[w];
    const int deg = cnt[w];
    const int end = beg + deg;

    float4 a0 = make_float4(0.f, 0.f, 0.f, 0.f);
    float4 a1 = make_float4(0.f, 0.f, 0.f, 0.f);
    int e = beg;
    for (; e + 3 < end; e += 4) {
        const int s0 = col[e], s1 = col[e + 1], s2 = col[e + 2], s3 = col[e + 3];
        const ushort4 v0 = *(const ushort4*)(Y + (size_t)s0 * 256 + c4);
        const ushort4 v1 = *(const ushort4*)(Y + (size_t)s1 * 256 + c4);
        const ushort4 v2 = *(const ushort4*)(Y + (size_t)s2 * 256 + c4);
        const ushort4 v3 = *(const ushort4*)(Y + (size_t)s3 * 256 + c4);
        a0.x += bf2f(v0.x) + bf2f(v1.x);  a1.x += bf2f(v2.x) + bf2f(v3.x);
        a0.y += bf2f(v0.y) + bf2f(v1.y);  a1.y += bf2f(v2.y) + bf2f(v3.y);
        a0.z += bf2f(v0.z) + bf2f(v1.z);  a1.z += bf2f(v2.z) + bf2f(v3.z);
        a0.w += bf2f(v0.w) + bf2f(v1.w);  a1.w += bf2f(v2.w) + bf2f(v3.w);
    }
    for (; e < end; ++e) {
        const ushort4 v0 = *(const ushort4*)(Y + (size_t)col[e] * 256 + c4);
        a0.x += bf2f(v0.x); a0.y += bf2f(v0.y);
        a0.z += bf2f(v0.z); a0.w += bf2f(v0.w);
    }
    float4 acc;
    acc.x = a0.x + a1.x; acc.y = a0.y + a1.y;
    acc.z = a0.z + a1.z; acc.w = a0.w + a1.w;

    const float inv = 1.0f / fmaxf((float)deg, 1.0f);
    float4 z;
    if (LAYER1) {
        const ushort4 zb = *(const ushort4*)((const unsigned short*)Z + (size_t)w * 256 + c4);
        z = make_float4(bf2f(zb.x), bf2f(zb.y), bf2f(zb.z), bf2f(zb.w));
    } else {
        z = *(const float4*)((const float*)Z + (size_t)w * 256 + c4);
    }
    float4 o;
    o.x = acc.x * inv + z.x;
    o.y = acc.y * inv + z.y;
    o.z = acc.z * inv + z.z;
    o.w = acc.w * inv + z.w;
    if (LAYER1) {
        o.x = fmaxf(o.x, 0.f); o.y = fmaxf(o.y, 0.f);
        o.z = fmaxf(o.z, 0.f); o.w = fmaxf(o.w, 0.f);
        ushort4 ob;
        ob.x = f2bf(o.x); ob.y = f2bf(o.y); ob.z = f2bf(o.z); ob.w = f2bf(o.w);
        *(ushort4*)((unsigned short*)OUT + (size_t)w * 256 + c4) = ob;
    } else {
        *(float4*)((float*)OUT + (size_t)w * 256 + c4) = o;
    }
}

// ---------------------------------------------------------------------------
extern "C" void kernel_launch(void* const* d_in, const int* in_sizes, int n_in,
                              void* d_out, int out_size, void* d_ws, size_t ws_size,
                              hipStream_t stream) {
    const float* x   = (const float*)d_in[0];
    const void*  ei  = d_in[1];
    const float* W1l = (const float*)d_in[2];
    const float* b1  = (const float*)d_in[3];
    const float* W1r = (const float*)d_in[4];
    const float* W2l = (const float*)d_in[5];
    const float* b2  = (const float*)d_in[6];
    const float* W2r = (const float*)d_in[7];

    const int N = in_sizes[0] / IN_CH;  // 100000
    const int E = in_sizes[1] / 2;      // 1000000

    char* ws = (char*)d_ws;
    size_t off = 0;
    auto alloc = [&](size_t bytes) {
        void* p = ws + off;
        off = (off + bytes + 255) & ~(size_t)255;
        return p;
    };
    int* flag    = (int*)alloc(4);
    int* cnt     = (int*)alloc((size_t)(N + 1) * 4);  // [N] counts + [1] counter
    int* counter = cnt + N;
    int* beg     = (int*)alloc((size_t)N * 4);
    int* cur     = (int*)alloc((size_t)N * 4);
    int* col     = (int*)alloc((size_t)E * 4);
    unsigned short* wt1 = (unsigned short*)alloc((size_t)512 * 320 * 2);
    unsigned short* wt2 = (unsigned short*)alloc((size_t)512 * 256 * 2);
    unsigned short* hb  = (unsigned short*)alloc((size_t)N * 256 * 2);  // h bf16
    unsigned short* y   = (unsigned short*)alloc((size_t)N * 256 * 2);  // y bf16

    float* out = (float*)d_out;
    unsigned short* z1 = (unsigned short*)d_out;  // layer-1 z bf16 scratch in d_out

    // ---- CSR build (by dst, unordered groups) ----
    hipMemsetAsync(cnt, 0, (size_t)(N + 1) * 4, stream);
    detect_idx_kernel<<<1, 64, 0, stream>>>(ei, flag);
    hist_kernel<<<(E + 255) / 256, 256, 0, stream>>>(ei, flag, cnt, E);
    offsets_kernel<<<(N + 255) / 256, 256, 0, stream>>>(cnt, counter, beg, cur, N);
    fill_kernel<<<(E + 255) / 256, 256, 0, stream>>>(ei, flag, cur, col, E);

    // ---- weight conversions ----
    convert_w_kernel<<<(512 * 320 + 255) / 256, 256, 0, stream>>>(W1l, W1r, wt1, IN_CH, 320);
    convert_w_kernel<<<(512 * 256 + 255) / 256, 256, 0, stream>>>(W2l, W2r, wt2, HID, 256);

    const int gblocks = (N + 127) / 128;  // one block per 128-row slab

    // ---- layer 1: y=x@W1l (bf16), z1(d_out,bf16)=x@W1r+b1 ; h=relu(mean+z1) ----
    mfma_gemm_kernel<320, true, true><<<gblocks, 256, 0, stream>>>(x, wt1, b1, y, z1, N);
    gather_agg_kernel<true><<<(N + 3) / 4, 256, 0, stream>>>(y, beg, cnt, col, z1, hb, N);

    // ---- layer 2: y=h@W2l, z(d_out,fp32)=h@W2r+b2 ; out = mean+z ----
    mfma_gemm_kernel<256, false, false><<<gblocks, 256, 0, stream>>>(hb, wt2, b2, y, out, N);
    gather_agg_kernel<false><<<(N + 3) / 4, 256, 0, stream>>>(y, beg, cnt, col, out, out, N);
}

// Round 8
// 533.392 us; speedup vs baseline: 1.0446x; 1.0446x over previous
//
#include <hip/hip_runtime.h>
#include <hip/hip_bf16.h>
#include <cstdint>
#include <cstddef>

#define IN_CH 312
#define HID 256

typedef __attribute__((ext_vector_type(8))) short bf16x8;
typedef __attribute__((ext_vector_type(4))) float f32x4;
typedef __attribute__((ext_vector_type(8))) unsigned short ushort8;

__device__ __forceinline__ unsigned short f2bf(float f) {
    union { float f; unsigned u; } v; v.f = f;
    const unsigned r = v.u + 0x7FFFu + ((v.u >> 16) & 1u);  // RNE
    return (unsigned short)(r >> 16);
}
__device__ __forceinline__ float bf2f(unsigned short s) {
    union { unsigned u; float f; } v; v.u = (unsigned)s << 16;
    return v.f;
}
__device__ __forceinline__ void gload_lds16(const void* g, void* l) {
    __builtin_amdgcn_global_load_lds(
        (const __attribute__((address_space(1))) void*)g,
        (__attribute__((address_space(3))) void*)l, 16, 0, 0);
}

// ---------------------------------------------------------------------------
// Index dtype detector (int64 vs int32 edge_index).
// ---------------------------------------------------------------------------
__global__ void detect_idx_kernel(const void* __restrict__ ei, int* __restrict__ flag) {
    if (blockIdx.x == 0 && threadIdx.x == 0) {
        const int* p = (const int*)ei;
        int ok = 1;
        for (int i = 0; i < 64; ++i) ok &= (p[2 * i + 1] == 0);
        *flag = ok;
    }
}
__device__ __forceinline__ long long load_idx(const void* ei, long long i, bool is64) {
    return is64 ? ((const long long*)ei)[i] : (long long)((const int*)ei)[i];
}

// ---------------------------------------------------------------------------
// CSR build (unordered groups): histogram -> atomic group-offset assignment
// -> atomic-cursor fill. Group placement nondeterministic, membership exact.
// ---------------------------------------------------------------------------
__global__ void hist_kernel(const void* __restrict__ ei, const int* __restrict__ flag,
                            int* __restrict__ cnt, int E) {
    const int i = blockIdx.x * blockDim.x + threadIdx.x;
    if (i >= E) return;
    const bool is64 = (*flag != 0);
    atomicAdd(&cnt[load_idx(ei, (long long)E + i, is64)], 1);
}

__global__ void offsets_kernel(const int* __restrict__ cnt, int* __restrict__ counter,
                               int* __restrict__ beg, int* __restrict__ cur, int n) {
    const int i = blockIdx.x * blockDim.x + threadIdx.x;
    if (i >= n) return;
    const int b = atomicAdd(counter, cnt[i]);
    beg[i] = b;
    cur[i] = b;
}

__global__ void fill_kernel(const void* __restrict__ ei, const int* __restrict__ flag,
                            int* __restrict__ cur, int* __restrict__ col, int E) {
    const int i = blockIdx.x * blockDim.x + threadIdx.x;
    if (i >= E) return;
    const bool is64 = (*flag != 0);
    const long long s = load_idx(ei, i, is64);
    const long long d = load_idx(ei, (long long)E + i, is64);
    col[atomicAdd(&cur[d], 1)] = (int)s;
}

// WcatT[c][k] = (c<256 ? Wl[k][c] : Wr[k][c-256]), bf16, k >= K zero-padded.
__global__ void convert_w_kernel(const float* __restrict__ Wl, const float* __restrict__ Wr,
                                 unsigned short* __restrict__ wt, int K, int Kpad) {
    const int tid = blockIdx.x * blockDim.x + threadIdx.x;
    if (tid >= 512 * Kpad) return;
    const int c = tid / Kpad;
    const int k = tid % Kpad;
    float v = 0.f;
    if (k < K) v = (c < 256) ? Wl[(size_t)k * 256 + c] : Wr[(size_t)k * 256 + (c - 256)];
    wt[(size_t)c * Kpad + k] = f2bf(v);
}

// ---------------------------------------------------------------------------
// MFMA GEMM: 128x128 tile, BK=64, 4 waves (2x2), 16x16x32 bf16 MFMA, 32 KB LDS.
// Grid (M/128, 4): blockIdx.x = row-slab (FASTEST), blockIdx.y = col-block
// (SLOWEST). Dispatch order => all 782 slabs of col-block 0 run first,
// streaming A into L3; col-blocks 1-3 then L3-hit A (temporal dedupe, R4
// counters: FETCH ~= A once). Avoids R6's concurrent cross-XCD miss races.
//   AFP32: A fp32 [M][312] reg-staged (float4 -> cvt -> swizzled ds_write).
//   else   A bf16 [M][KPAD] via global_load_lds (pre-swizzled source).
// Output: c0<256 -> Y bf16; else Z = acc+bias (ZBF16 ? bf16 : fp32).
// bf16 outputs via LDS-staged transpose -> ushort8 coalesced stores.
// ---------------------------------------------------------------------------
template <int KPAD, bool AFP32, bool ZBF16>
__global__ __launch_bounds__(256) void mfma_gemm_kernel(
    const void* __restrict__ Avoid,         // [M][312] f32  or  [M][KPAD] bf16
    const unsigned short* __restrict__ WT,  // [512][KPAD] bf16
    const float* __restrict__ bias,         // [256]
    unsigned short* __restrict__ Y,         // [M][256] bf16
    void* __restrict__ Z,                   // [M][256] bf16 or fp32
    int M)
{
    __shared__ __align__(16) char smem[32768];
    short* a_lds = (short*)smem;             // [128*64] bf16 (16 KB)
    short* b_lds = (short*)(smem + 16384);   // [128*64] bf16 (16 KB)

    const int lane = threadIdx.x & 63;
    const int wid  = threadIdx.x >> 6;
    const int wr = wid >> 1, wc = wid & 1;
    const int r0 = blockIdx.x * 128;   // row-slab fastest
    const int c0 = blockIdx.y * 128;   // col-block slowest -> L3 temporal dedupe

    f32x4 acc[4][4];
    #pragma unroll
    for (int i = 0; i < 4; ++i)
        #pragma unroll
        for (int j = 0; j < 4; ++j) acc[i][j] = (f32x4)0.f;

    // gload staging geometry: wave-load ld covers tile rows ld*8..ld*8+7;
    // lane l -> row ld*8 + (l>>3), source 16B chunk (l&7) ^ (l>>3).
    const int ldrow  = lane >> 3;
    const int schunk = (lane & 7) ^ ldrow;

    for (int kb = 0; kb < KPAD; kb += 64) {
        __syncthreads();
        // ---- B tile: 128 rows x 128B, 16 wave-loads ----
        #pragma unroll
        for (int j = 0; j < 4; ++j) {
            const int ld = wid * 4 + j;
            const int trow = ld * 8 + ldrow;
            gload_lds16(WT + (size_t)(c0 + trow) * KPAD + kb + schunk * 8,
                        (char*)b_lds + ld * 1024);
        }
        // ---- A tile: 128 rows x 128B ----
        if (AFP32) {
            const float* A = (const float*)Avoid;  // stride IN_CH
            #pragma unroll
            for (int g = 0; g < 2; ++g) {
                float4 v[4];
                #pragma unroll
                for (int it = 0; it < 4; ++it) {
                    const int idx = (int)threadIdx.x + (g * 4 + it) * 256;
                    const int row = idx >> 4, q = idx & 15;
                    const int gr = min(r0 + row, M - 1);
                    const int gk = kb + q * 4;  // quad-aligned; IN_CH%4==0
                    v[it] = (gk < IN_CH) ? *(const float4*)(A + (size_t)gr * IN_CH + gk)
                                         : make_float4(0.f, 0.f, 0.f, 0.f);
                }
                #pragma unroll
                for (int it = 0; it < 4; ++it) {
                    const int idx = (int)threadIdx.x + (g * 4 + it) * 256;
                    const int row = idx >> 4, q = idx & 15;
                    ushort4 b4;
                    b4.x = f2bf(v[it].x); b4.y = f2bf(v[it].y);
                    b4.z = f2bf(v[it].z); b4.w = f2bf(v[it].w);
                    const int byte = row * 128 + (((q >> 1) ^ (row & 7)) * 16) + (q & 1) * 8;
                    *(ushort4*)((char*)a_lds + byte) = b4;
                }
            }
        } else {
            const unsigned short* A = (const unsigned short*)Avoid;  // stride KPAD
            #pragma unroll
            for (int j = 0; j < 4; ++j) {
                const int ld = wid * 4 + j;
                const int trow = ld * 8 + ldrow;
                const int gr = min(r0 + trow, M - 1);
                gload_lds16(A + (size_t)gr * KPAD + kb + schunk * 8,
                            (char*)a_lds + ld * 1024);
            }
        }
        __syncthreads();

        #pragma unroll
        for (int ks = 0; ks < 2; ++ks) {
            bf16x8 af[4], bg[4];
            #pragma unroll
            for (int f = 0; f < 4; ++f) {
                const int arow = wr * 64 + f * 16 + (lane & 15);
                const int ach  = (ks * 4 + (lane >> 4)) ^ (arow & 7);
                af[f] = *(const bf16x8*)((const char*)a_lds + arow * 128 + ach * 16);
                const int brow = wc * 64 + f * 16 + (lane & 15);
                const int bch  = (ks * 4 + (lane >> 4)) ^ (brow & 7);
                bg[f] = *(const bf16x8*)((const char*)b_lds + brow * 128 + bch * 16);
            }
            #pragma unroll
            for (int fm = 0; fm < 4; ++fm)
                #pragma unroll
                for (int fn = 0; fn < 4; ++fn)
                    acc[fm][fn] = __builtin_amdgcn_mfma_f32_16x16x32_bf16(
                        af[fm], bg[fn], acc[fm][fn], 0, 0, 0);
        }
    }

    // epilogue. C/D layout: col=lane&15, row=(lane>>4)*4+reg  [m89]
    const bool isY = (c0 < 256);
    const int cloc = wc * 64 + (lane & 15);

    if (isY || ZBF16) {
        // bf16 output via LDS transpose, two 64-row halves (reuses smem)
        constexpr int CST = 136;  // shorts; keeps 16B align, spreads banks
        short* c_lds = (short*)smem;
        float bv4[4];
        #pragma unroll
        for (int fn = 0; fn < 4; ++fn) {
            const int bidx = max(0, c0 - 256) + cloc + fn * 16;  // safe even if isY
            bv4[fn] = isY ? 0.f : bias[bidx];
        }
        #pragma unroll
        for (int h = 0; h < 2; ++h) {
            __syncthreads();
            if (wr == h) {
                #pragma unroll
                for (int fm = 0; fm < 4; ++fm)
                    #pragma unroll
                    for (int fn = 0; fn < 4; ++fn)
                        #pragma unroll
                        for (int r = 0; r < 4; ++r)
                            c_lds[(fm * 16 + (lane >> 4) * 4 + r) * CST + cloc + fn * 16] =
                                (short)f2bf(acc[fm][fn][r] + bv4[fn]);
            }
            __syncthreads();
            const int row = (int)threadIdx.x >> 2;          // 0..63
            const int cb  = ((int)threadIdx.x & 3) * 32;    // 0,32,64,96
            const int gr  = r0 + h * 64 + row;
            if (gr < M) {
                unsigned short* dst = isY
                    ? (Y + (size_t)gr * 256 + c0 + cb)
                    : ((unsigned short*)Z + (size_t)gr * 256 + (c0 - 256) + cb);
                #pragma unroll
                for (int j = 0; j < 4; ++j)
                    *(ushort8*)(dst + j * 8) =
                        *(const ushort8*)&c_lds[row * CST + cb + j * 8];
            }
        }
    } else {
        // Z fp32 direct scalar stores (layer 2; in-place target in d_out)
        const int rbase = r0 + wr * 64 + (lane >> 4) * 4;
        #pragma unroll
        for (int fn = 0; fn < 4; ++fn) {
            const int gc = (c0 - 256) + cloc + fn * 16;
            const float bvv = bias[gc];
            #pragma unroll
            for (int fm = 0; fm < 4; ++fm)
                #pragma unroll
                for (int r = 0; r < 4; ++r) {
                    const int gr = rbase + fm * 16 + r;
                    if (gr < M) ((float*)Z)[(size_t)gr * 256 + gc] = acc[fm][fn][r] + bvv;
                }
        }
    }
}

// ---------------------------------------------------------------------------
// Gather aggregation over bf16 y: out[i] = act( mean_{e}(y[col[e]]) + Z[i] ).
// LAYER1: Z bf16, act=relu, write bf16 h. else: Z fp32, write fp32 d_out.
// Unroll-4 with two accumulator chains for ILP.
// ---------------------------------------------------------------------------
template <bool LAYER1>
__global__ void gather_agg_kernel(const unsigned short* __restrict__ Y,
                                  const int* __restrict__ beg_arr,
                                  const int* __restrict__ cnt,
                                  const int* __restrict__ col,
                                  const void* __restrict__ Z,
                                  void* __restrict__ OUT, int N)
{
    const long long gw = ((long long)blockIdx.x * blockDim.x + threadIdx.x) >> 6;
    if (gw >= N) return;
    const int w = (int)gw;
    const int lane = threadIdx.x & 63;
    const int c4 = lane * 4;
    const int beg = beg_arr[w];
    const int deg = cnt[w];
    const int end = beg + deg;

    float4 a0 = make_float4(0.f, 0.f, 0.f, 0.f);
    float4 a1 = make_float4(0.f, 0.f, 0.f, 0.f);
    int e = beg;
    for (; e + 3 < end; e += 4) {
        const int s0 = col[e], s1 = col[e + 1], s2 = col[e + 2], s3 = col[e + 3];
        const ushort4 v0 = *(const ushort4*)(Y + (size_t)s0 * 256 + c4);
        const ushort4 v1 = *(const ushort4*)(Y + (size_t)s1 * 256 + c4);
        const ushort4 v2 = *(const ushort4*)(Y + (size_t)s2 * 256 + c4);
        const ushort4 v3 = *(const ushort4*)(Y + (size_t)s3 * 256 + c4);
        a0.x += bf2f(v0.x) + bf2f(v1.x);  a1.x += bf2f(v2.x) + bf2f(v3.x);
        a0.y += bf2f(v0.y) + bf2f(v1.y);  a1.y += bf2f(v2.y) + bf2f(v3.y);
        a0.z += bf2f(v0.z) + bf2f(v1.z);  a1.z += bf2f(v2.z) + bf2f(v3.z);
        a0.w += bf2f(v0.w) + bf2f(v1.w);  a1.w += bf2f(v2.w) + bf2f(v3.w);
    }
    for (; e < end; ++e) {
        const ushort4 v0 = *(const ushort4*)(Y + (size_t)col[e] * 256 + c4);
        a0.x += bf2f(v0.x); a0.y += bf2f(v0.y);
        a0.z += bf2f(v0.z); a0.w += bf2f(v0.w);
    }
    float4 acc;
    acc.x = a0.x + a1.x; acc.y = a0.y + a1.y;
    acc.z = a0.z + a1.z; acc.w = a0.w + a1.w;

    const float inv = 1.0f / fmaxf((float)deg, 1.0f);
    float4 z;
    if (LAYER1) {
        const ushort4 zb = *(const ushort4*)((const unsigned short*)Z + (size_t)w * 256 + c4);
        z = make_float4(bf2f(zb.x), bf2f(zb.y), bf2f(zb.z), bf2f(zb.w));
    } else {
        z = *(const float4*)((const float*)Z + (size_t)w * 256 + c4);
    }
    float4 o;
    o.x = acc.x * inv + z.x;
    o.y = acc.y * inv + z.y;
    o.z = acc.z * inv + z.z;
    o.w = acc.w * inv + z.w;
    if (LAYER1) {
        o.x = fmaxf(o.x, 0.f); o.y = fmaxf(o.y, 0.f);
        o.z = fmaxf(o.z, 0.f); o.w = fmaxf(o.w, 0.f);
        ushort4 ob;
        ob.x = f2bf(o.x); ob.y = f2bf(o.y); ob.z = f2bf(o.z); ob.w = f2bf(o.w);
        *(ushort4*)((unsigned short*)OUT + (size_t)w * 256 + c4) = ob;
    } else {
        *(float4*)((float*)OUT + (size_t)w * 256 + c4) = o;
    }
}

// ---------------------------------------------------------------------------
extern "C" void kernel_launch(void* const* d_in, const int* in_sizes, int n_in,
                              void* d_out, int out_size, void* d_ws, size_t ws_size,
                              hipStream_t stream) {
    const float* x   = (const float*)d_in[0];
    const void*  ei  = d_in[1];
    const float* W1l = (const float*)d_in[2];
    const float* b1  = (const float*)d_in[3];
    const float* W1r = (const float*)d_in[4];
    const float* W2l = (const float*)d_in[5];
    const float* b2  = (const float*)d_in[6];
    const float* W2r = (const float*)d_in[7];

    const int N = in_sizes[0] / IN_CH;  // 100000
    const int E = in_sizes[1] / 2;      // 1000000

    char* ws = (char*)d_ws;
    size_t off = 0;
    auto alloc = [&](size_t bytes) {
        void* p = ws + off;
        off = (off + bytes + 255) & ~(size_t)255;
        return p;
    };
    int* flag    = (int*)alloc(4);
    int* cnt     = (int*)alloc((size_t)(N + 1) * 4);  // [N] counts + [1] counter
    int* counter = cnt + N;
    int* beg     = (int*)alloc((size_t)N * 4);
    int* cur     = (int*)alloc((size_t)N * 4);
    int* col     = (int*)alloc((size_t)E * 4);
    unsigned short* wt1 = (unsigned short*)alloc((size_t)512 * 320 * 2);
    unsigned short* wt2 = (unsigned short*)alloc((size_t)512 * 256 * 2);
    unsigned short* hb  = (unsigned short*)alloc((size_t)N * 256 * 2);  // h bf16
    unsigned short* y   = (unsigned short*)alloc((size_t)N * 256 * 2);  // y bf16

    float* out = (float*)d_out;
    unsigned short* z1 = (unsigned short*)d_out;  // layer-1 z bf16 scratch in d_out

    // ---- CSR build (by dst, unordered groups) ----
    hipMemsetAsync(cnt, 0, (size_t)(N + 1) * 4, stream);
    detect_idx_kernel<<<1, 64, 0, stream>>>(ei, flag);
    hist_kernel<<<(E + 255) / 256, 256, 0, stream>>>(ei, flag, cnt, E);
    offsets_kernel<<<(N + 255) / 256, 256, 0, stream>>>(cnt, counter, beg, cur, N);
    fill_kernel<<<(E + 255) / 256, 256, 0, stream>>>(ei, flag, cur, col, E);

    // ---- weight conversions ----
    convert_w_kernel<<<(512 * 320 + 255) / 256, 256, 0, stream>>>(W1l, W1r, wt1, IN_CH, 320);
    convert_w_kernel<<<(512 * 256 + 255) / 256, 256, 0, stream>>>(W2l, W2r, wt2, HID, 256);

    const dim3 ggrid((N + 127) / 128, 4);  // row-slab fastest, col-block slowest

    // ---- layer 1: y=x@W1l (bf16), z1(d_out,bf16)=x@W1r+b1 ; h=relu(mean+z1) ----
    mfma_gemm_kernel<320, true, true><<<ggrid, 256, 0, stream>>>(x, wt1, b1, y, z1, N);
    gather_agg_kernel<true><<<(N + 3) / 4, 256, 0, stream>>>(y, beg, cnt, col, z1, hb, N);

    // ---- layer 2: y=h@W2l, z(d_out,fp32)=h@W2r+b2 ; out = mean+z ----
    mfma_gemm_kernel<256, false, false><<<ggrid, 256, 0, stream>>>(hb, wt2, b2, y, out, N);
    gather_agg_kernel<false><<<(N + 3) / 4, 256, 0, stream>>>(y, beg, cnt, col, out, out, N);
}

// Round 9
// 486.720 us; speedup vs baseline: 1.1448x; 1.0959x over previous
//
#include <hip/hip_runtime.h>
#include <hip/hip_bf16.h>
#include <cstdint>
#include <cstddef>

#define IN_CH 312
#define HID 256

typedef __attribute__((ext_vector_type(8))) short bf16x8;
typedef __attribute__((ext_vector_type(4))) float f32x4;
typedef __attribute__((ext_vector_type(8))) unsigned short ushort8;

__device__ __forceinline__ unsigned short f2bf(float f) {
    union { float f; unsigned u; } v; v.f = f;
    const unsigned r = v.u + 0x7FFFu + ((v.u >> 16) & 1u);  // RNE
    return (unsigned short)(r >> 16);
}
__device__ __forceinline__ float bf2f(unsigned short s) {
    union { unsigned u; float f; } v; v.u = (unsigned)s << 16;
    return v.f;
}
__device__ __forceinline__ void gload_lds16(const void* g, void* l) {
    __builtin_amdgcn_global_load_lds(
        (const __attribute__((address_space(1))) void*)g,
        (__attribute__((address_space(3))) void*)l, 16, 0, 0);
}

// ---------------------------------------------------------------------------
// Index dtype detector (int64 vs int32 edge_index).
// ---------------------------------------------------------------------------
__global__ void detect_idx_kernel(const void* __restrict__ ei, int* __restrict__ flag) {
    if (blockIdx.x == 0 && threadIdx.x == 0) {
        const int* p = (const int*)ei;
        int ok = 1;
        for (int i = 0; i < 64; ++i) ok &= (p[2 * i + 1] == 0);
        *flag = ok;
    }
}
__device__ __forceinline__ long long load_idx(const void* ei, long long i, bool is64) {
    return is64 ? ((const long long*)ei)[i] : (long long)((const int*)ei)[i];
}

// ---------------------------------------------------------------------------
// CSR build (unordered groups): histogram -> atomic group-offset assignment
// -> atomic-cursor fill. Group placement nondeterministic, membership exact.
// ---------------------------------------------------------------------------
__global__ void hist_kernel(const void* __restrict__ ei, const int* __restrict__ flag,
                            int* __restrict__ cnt, int E) {
    const int i = blockIdx.x * blockDim.x + threadIdx.x;
    if (i >= E) return;
    const bool is64 = (*flag != 0);
    atomicAdd(&cnt[load_idx(ei, (long long)E + i, is64)], 1);
}

__global__ void offsets_kernel(const int* __restrict__ cnt, int* __restrict__ counter,
                               int* __restrict__ beg, int* __restrict__ cur, int n) {
    const int i = blockIdx.x * blockDim.x + threadIdx.x;
    if (i >= n) return;
    const int b = atomicAdd(counter, cnt[i]);
    beg[i] = b;
    cur[i] = b;
}

__global__ void fill_kernel(const void* __restrict__ ei, const int* __restrict__ flag,
                            int* __restrict__ cur, int* __restrict__ col, int E) {
    const int i = blockIdx.x * blockDim.x + threadIdx.x;
    if (i >= E) return;
    const bool is64 = (*flag != 0);
    const long long s = load_idx(ei, i, is64);
    const long long d = load_idx(ei, (long long)E + i, is64);
    col[atomicAdd(&cur[d], 1)] = (int)s;
}

// WcatT[c][k] = (c<256 ? Wl[k][c] : Wr[k][c-256]), bf16, k >= K zero-padded.
__global__ void convert_w_kernel(const float* __restrict__ Wl, const float* __restrict__ Wr,
                                 unsigned short* __restrict__ wt, int K, int Kpad) {
    const int tid = blockIdx.x * blockDim.x + threadIdx.x;
    if (tid >= 512 * Kpad) return;
    const int c = tid / Kpad;
    const int k = tid % Kpad;
    float v = 0.f;
    if (k < K) v = (c < 256) ? Wl[(size_t)k * 256 + c] : Wr[(size_t)k * 256 + (c - 256)];
    wt[(size_t)c * Kpad + k] = f2bf(v);
}

// ---------------------------------------------------------------------------
// MFMA GEMM: 128x256 tile (2 col-blocks total -> A logically re-read 2x, not
// 4x), BK=64, 8 waves (4x2), wave tile 32x128, 16x16x32 bf16 MFMA.
// LDS: A 16 KB + B 32 KB = 48 KB. Grid (M/128, 2): y=0 -> Y, y=1 -> Z.
//   AFP32: A fp32 [M][312] reg-staged (float4 -> cvt -> swizzled ds_write).
//   else   A bf16 [M][KPAD] via global_load_lds (pre-swizzled source).
// bf16 outputs via LDS-staged transpose (two 64-row halves, c_lds reuses
// smem) -> ushort8 coalesced stores; layer-2 Z = fp32 scalar stores.
// ---------------------------------------------------------------------------
template <int KPAD, bool AFP32, bool ZBF16>
__global__ __launch_bounds__(512) void mfma_gemm_kernel(
    const void* __restrict__ Avoid,         // [M][312] f32  or  [M][KPAD] bf16
    const unsigned short* __restrict__ WT,  // [512][KPAD] bf16
    const float* __restrict__ bias,         // [256]
    unsigned short* __restrict__ Y,         // [M][256] bf16
    void* __restrict__ Z,                   // [M][256] bf16 or fp32
    int M)
{
    __shared__ __align__(16) char smem[49152];
    short* a_lds = (short*)smem;             // [128*64] bf16 (16 KB)
    short* b_lds = (short*)(smem + 16384);   // [256*64] bf16 (32 KB)

    const int tid  = (int)threadIdx.x;
    const int lane = tid & 63;
    const int wid  = tid >> 6;           // 0..7
    const int wr = wid >> 1, wc = wid & 1;  // 4 wave-rows x 2 wave-cols
    const int r0 = blockIdx.x * 128;     // row-slab fastest
    const int c0 = blockIdx.y * 256;     // 0 -> Y, 256 -> Z

    f32x4 acc[2][8];
    #pragma unroll
    for (int i = 0; i < 2; ++i)
        #pragma unroll
        for (int j = 0; j < 8; ++j) acc[i][j] = (f32x4)0.f;

    // gload staging geometry: wave-load ld covers tile rows ld*8..ld*8+7;
    // lane l -> row ld*8 + (l>>3), source 16B chunk (l&7) ^ (l>>3).
    const int ldrow  = lane >> 3;
    const int schunk = (lane & 7) ^ ldrow;

    for (int kb = 0; kb < KPAD; kb += 64) {
        __syncthreads();
        // ---- B tile: 256 rows x 128B, 32 wave-loads (4/wave) ----
        #pragma unroll
        for (int j = 0; j < 4; ++j) {
            const int ld = wid * 4 + j;
            const int trow = ld * 8 + ldrow;
            gload_lds16(WT + (size_t)(c0 + trow) * KPAD + kb + schunk * 8,
                        (char*)b_lds + ld * 1024);
        }
        // ---- A tile: 128 rows x 128B ----
        if (AFP32) {
            const float* A = (const float*)Avoid;  // stride IN_CH
            float4 v[4];
            #pragma unroll
            for (int it = 0; it < 4; ++it) {
                const int idx = tid + it * 512;
                const int row = idx >> 4, q = idx & 15;
                const int gr = min(r0 + row, M - 1);
                const int gk = kb + q * 4;  // quad-aligned; IN_CH%4==0
                v[it] = (gk < IN_CH) ? *(const float4*)(A + (size_t)gr * IN_CH + gk)
                                     : make_float4(0.f, 0.f, 0.f, 0.f);
            }
            #pragma unroll
            for (int it = 0; it < 4; ++it) {
                const int idx = tid + it * 512;
                const int row = idx >> 4, q = idx & 15;
                ushort4 b4;
                b4.x = f2bf(v[it].x); b4.y = f2bf(v[it].y);
                b4.z = f2bf(v[it].z); b4.w = f2bf(v[it].w);
                const int byte = row * 128 + (((q >> 1) ^ (row & 7)) * 16) + (q & 1) * 8;
                *(ushort4*)((char*)a_lds + byte) = b4;
            }
        } else {
            const unsigned short* A = (const unsigned short*)Avoid;  // stride KPAD
            #pragma unroll
            for (int j = 0; j < 2; ++j) {
                const int ld = wid * 2 + j;
                const int trow = ld * 8 + ldrow;
                const int gr = min(r0 + trow, M - 1);
                gload_lds16(A + (size_t)gr * KPAD + kb + schunk * 8,
                            (char*)a_lds + ld * 1024);
            }
        }
        __syncthreads();

        #pragma unroll
        for (int ks = 0; ks < 2; ++ks) {
            bf16x8 af[2], bg[8];
            #pragma unroll
            for (int f = 0; f < 2; ++f) {
                const int arow = wr * 32 + f * 16 + (lane & 15);
                const int ach  = (ks * 4 + (lane >> 4)) ^ (arow & 7);
                af[f] = *(const bf16x8*)((const char*)a_lds + arow * 128 + ach * 16);
            }
            #pragma unroll
            for (int f = 0; f < 8; ++f) {
                const int brow = wc * 128 + f * 16 + (lane & 15);
                const int bch  = (ks * 4 + (lane >> 4)) ^ (brow & 7);
                bg[f] = *(const bf16x8*)((const char*)b_lds + brow * 128 + bch * 16);
            }
            #pragma unroll
            for (int fm = 0; fm < 2; ++fm)
                #pragma unroll
                for (int fn = 0; fn < 8; ++fn)
                    acc[fm][fn] = __builtin_amdgcn_mfma_f32_16x16x32_bf16(
                        af[fm], bg[fn], acc[fm][fn], 0, 0, 0);
        }
    }

    // epilogue. C/D layout: col=lane&15, row=(lane>>4)*4+reg  [m89]
    const bool isY = (c0 == 0);
    const int cloc = wc * 128 + (lane & 15);  // 0..255 within tile

    if (isY || ZBF16) {
        // bf16 out via LDS transpose, two 64-row halves; c_lds reuses smem
        constexpr int CST = 264;  // shorts/row: 528B, keeps 16B align
        short* c_lds = (short*)smem;
        float bv4[8];
        #pragma unroll
        for (int fn = 0; fn < 8; ++fn)
            bv4[fn] = isY ? 0.f : bias[cloc + fn * 16];
        #pragma unroll
        for (int h = 0; h < 2; ++h) {
            __syncthreads();
            if ((wr >> 1) == h) {
                const int lr0 = (wr & 1) * 32 + (lane >> 4) * 4;
                #pragma unroll
                for (int fm = 0; fm < 2; ++fm)
                    #pragma unroll
                    for (int fn = 0; fn < 8; ++fn)
                        #pragma unroll
                        for (int r = 0; r < 4; ++r)
                            c_lds[(lr0 + fm * 16 + r) * CST + cloc + fn * 16] =
                                (short)f2bf(acc[fm][fn][r] + bv4[fn]);
            }
            __syncthreads();
            const int row = tid >> 3;             // 0..63
            const int cb  = (tid & 7) * 32;       // 0..224
            const int gr  = r0 + h * 64 + row;
            if (gr < M) {
                unsigned short* dst = isY
                    ? (Y + (size_t)gr * 256 + cb)
                    : ((unsigned short*)Z + (size_t)gr * 256 + cb);
                #pragma unroll
                for (int j = 0; j < 4; ++j)
                    *(ushort8*)(dst + j * 8) =
                        *(const ushort8*)&c_lds[row * CST + cb + j * 8];
            }
        }
    } else {
        // Z fp32 direct scalar stores (layer 2; in-place target in d_out)
        const int rbase = r0 + wr * 32 + (lane >> 4) * 4;
        #pragma unroll
        for (int fn = 0; fn < 8; ++fn) {
            const int gc = cloc + fn * 16;
            const float bvv = bias[gc];
            #pragma unroll
            for (int fm = 0; fm < 2; ++fm)
                #pragma unroll
                for (int r = 0; r < 4; ++r) {
                    const int gr = rbase + fm * 16 + r;
                    if (gr < M) ((float*)Z)[(size_t)gr * 256 + gc] = acc[fm][fn][r] + bvv;
                }
        }
    }
}

// ---------------------------------------------------------------------------
// Gather aggregation over bf16 y: out[i] = act( mean_{e}(y[col[e]]) + Z[i] ).
// LAYER1: Z bf16, act=relu, write bf16 h. else: Z fp32, write fp32 d_out.
// Unroll-4 with two accumulator chains for ILP.
// ---------------------------------------------------------------------------
template <bool LAYER1>
__global__ void gather_agg_kernel(const unsigned short* __restrict__ Y,
                                  const int* __restrict__ beg_arr,
                                  const int* __restrict__ cnt,
                                  const int* __restrict__ col,
                                  const void* __restrict__ Z,
                                  void* __restrict__ OUT, int N)
{
    const long long gw = ((long long)blockIdx.x * blockDim.x + threadIdx.x) >> 6;
    if (gw >= N) return;
    const int w = (int)gw;
    const int lane = threadIdx.x & 63;
    const int c4 = lane * 4;
    const int beg = beg_arr[w];
    const int deg = cnt[w];
    const int end = beg + deg;

    float4 a0 = make_float4(0.f, 0.f, 0.f, 0.f);
    float4 a1 = make_float4(0.f, 0.f, 0.f, 0.f);
    int e = beg;
    for (; e + 3 < end; e += 4) {
        const int s0 = col[e], s1 = col[e + 1], s2 = col[e + 2], s3 = col[e + 3];
        const ushort4 v0 = *(const ushort4*)(Y + (size_t)s0 * 256 + c4);
        const ushort4 v1 = *(const ushort4*)(Y + (size_t)s1 * 256 + c4);
        const ushort4 v2 = *(const ushort4*)(Y + (size_t)s2 * 256 + c4);
        const ushort4 v3 = *(const ushort4*)(Y + (size_t)s3 * 256 + c4);
        a0.x += bf2f(v0.x) + bf2f(v1.x);  a1.x += bf2f(v2.x) + bf2f(v3.x);
        a0.y += bf2f(v0.y) + bf2f(v1.y);  a1.y += bf2f(v2.y) + bf2f(v3.y);
        a0.z += bf2f(v0.z) + bf2f(v1.z);  a1.z += bf2f(v2.z) + bf2f(v3.z);
        a0.w += bf2f(v0.w) + bf2f(v1.w);  a1.w += bf2f(v2.w) + bf2f(v3.w);
    }
    for (; e < end; ++e) {
        const ushort4 v0 = *(const ushort4*)(Y + (size_t)col[e] * 256 + c4);
        a0.x += bf2f(v0.x); a0.y += bf2f(v0.y);
        a0.z += bf2f(v0.z); a0.w += bf2f(v0.w);
    }
    float4 acc;
    acc.x = a0.x + a1.x; acc.y = a0.y + a1.y;
    acc.z = a0.z + a1.z; acc.w = a0.w + a1.w;

    const float inv = 1.0f / fmaxf((float)deg, 1.0f);
    float4 z;
    if (LAYER1) {
        const ushort4 zb = *(const ushort4*)((const unsigned short*)Z + (size_t)w * 256 + c4);
        z = make_float4(bf2f(zb.x), bf2f(zb.y), bf2f(zb.z), bf2f(zb.w));
    } else {
        z = *(const float4*)((const float*)Z + (size_t)w * 256 + c4);
    }
    float4 o;
    o.x = acc.x * inv + z.x;
    o.y = acc.y * inv + z.y;
    o.z = acc.z * inv + z.z;
    o.w = acc.w * inv + z.w;
    if (LAYER1) {
        o.x = fmaxf(o.x, 0.f); o.y = fmaxf(o.y, 0.f);
        o.z = fmaxf(o.z, 0.f); o.w = fmaxf(o.w, 0.f);
        ushort4 ob;
        ob.x = f2bf(o.x); ob.y = f2bf(o.y); ob.z = f2bf(o.z); ob.w = f2bf(o.w);
        *(ushort4*)((unsigned short*)OUT + (size_t)w * 256 + c4) = ob;
    } else {
        *(float4*)((float*)OUT + (size_t)w * 256 + c4) = o;
    }
}

// ---------------------------------------------------------------------------
extern "C" void kernel_launch(void* const* d_in, const int* in_sizes, int n_in,
                              void* d_out, int out_size, void* d_ws, size_t ws_size,
                              hipStream_t stream) {
    const float* x   = (const float*)d_in[0];
    const void*  ei  = d_in[1];
    const float* W1l = (const float*)d_in[2];
    const float* b1  = (const float*)d_in[3];
    const float* W1r = (const float*)d_in[4];
    const float* W2l = (const float*)d_in[5];
    const float* b2  = (const float*)d_in[6];
    const float* W2r = (const float*)d_in[7];

    const int N = in_sizes[0] / IN_CH;  // 100000
    const int E = in_sizes[1] / 2;      // 1000000

    char* ws = (char*)d_ws;
    size_t off = 0;
    auto alloc = [&](size_t bytes) {
        void* p = ws + off;
        off = (off + bytes + 255) & ~(size_t)255;
        return p;
    };
    int* flag    = (int*)alloc(4);
    int* cnt     = (int*)alloc((size_t)(N + 1) * 4);  // [N] counts + [1] counter
    int* counter = cnt + N;
    int* beg     = (int*)alloc((size_t)N * 4);
    int* cur     = (int*)alloc((size_t)N * 4);
    int* col     = (int*)alloc((size_t)E * 4);
    unsigned short* wt1 = (unsigned short*)alloc((size_t)512 * 320 * 2);
    unsigned short* wt2 = (unsigned short*)alloc((size_t)512 * 256 * 2);
    unsigned short* hb  = (unsigned short*)alloc((size_t)N * 256 * 2);  // h bf16
    unsigned short* y   = (unsigned short*)alloc((size_t)N * 256 * 2);  // y bf16

    float* out = (float*)d_out;
    unsigned short* z1 = (unsigned short*)d_out;  // layer-1 z bf16 scratch in d_out

    // ---- CSR build (by dst, unordered groups) ----
    hipMemsetAsync(cnt, 0, (size_t)(N + 1) * 4, stream);
    detect_idx_kernel<<<1, 64, 0, stream>>>(ei, flag);
    hist_kernel<<<(E + 255) / 256, 256, 0, stream>>>(ei, flag, cnt, E);
    offsets_kernel<<<(N + 255) / 256, 256, 0, stream>>>(cnt, counter, beg, cur, N);
    fill_kernel<<<(E + 255) / 256, 256, 0, stream>>>(ei, flag, cur, col, E);

    // ---- weight conversions ----
    convert_w_kernel<<<(512 * 320 + 255) / 256, 256, 0, stream>>>(W1l, W1r, wt1, IN_CH, 320);
    convert_w_kernel<<<(512 * 256 + 255) / 256, 256, 0, stream>>>(W2l, W2r, wt2, HID, 256);

    const dim3 ggrid((N + 127) / 128, 2);  // row-slab fastest; y: 0=Y block, 1=Z block

    // ---- layer 1: y=x@W1l (bf16), z1(d_out,bf16)=x@W1r+b1 ; h=relu(mean+z1) ----
    mfma_gemm_kernel<320, true, true><<<ggrid, 512, 0, stream>>>(x, wt1, b1, y, z1, N);
    gather_agg_kernel<true><<<(N + 3) / 4, 256, 0, stream>>>(y, beg, cnt, col, z1, hb, N);

    // ---- layer 2: y=h@W2l, z(d_out,fp32)=h@W2r+b2 ; out = mean+z ----
    mfma_gemm_kernel<256, false, false><<<ggrid, 512, 0, stream>>>(hb, wt2, b2, y, out, N);
    gather_agg_kernel<false><<<(N + 3) / 4, 256, 0, stream>>>(y, beg, cnt, col, out, out, N);
}